// Round 14
// baseline (323.613 us; speedup 1.0000x reference)
//
#include <hip/hip_runtime.h>
#include <hip/hip_bf16.h>
#include <math.h>

// Problem constants (BN, N, FIN, FO, H) from the reference
#define BN_   4
#define NN_   2048
#define FIN_  128
#define FO_   64
#define H_    4
#define D_    256   // FO*H

typedef __attribute__((ext_vector_type(8))) short bf16x8;   // 8 bf16 = 4 VGPRs
typedef __attribute__((ext_vector_type(4))) float floatx4;  // MFMA C/D frag

#define LOG2E 1.4426950408889634f
#define C2F   (0.2f * 1.4426950408889634f)   // 0.2 * log2(e)

#if __has_builtin(__builtin_amdgcn_exp2f)
#define EXP2(x) __builtin_amdgcn_exp2f(x)
#else
#define EXP2(x) exp2f(x)
#endif

__device__ __forceinline__ float bf2f(short u) {
    union { unsigned int i; float f; } v;
    v.i = ((unsigned int)(unsigned short)u) << 16;
    return v.f;
}
__device__ __forceinline__ short f2bf(float f) {
    union { float f; unsigned int u; } v; v.f = f;
    unsigned int r = v.u + 0x7fffu + ((v.u >> 16) & 1u);  // RNE
    return (short)(unsigned short)(r >> 16);
}

// pack two floats to two bf16 (RNE) in one dword; elem0 in low 16 bits
#if defined(__BF16_MANT_DIG__)
typedef __bf16 bfr2 __attribute__((ext_vector_type(2)));
__device__ __forceinline__ unsigned int pack_bf16(float a, float b) {
    union { bfr2 h; unsigned int u; } v;
    v.h = (bfr2){(__bf16)a, (__bf16)b};
    return v.u;
}
#else
__device__ __forceinline__ unsigned int pack_bf16(float a, float b) {
    return ((unsigned int)(unsigned short)f2bf(a)) |
           (((unsigned int)(unsigned short)f2bf(b)) << 16);
}
#endif

// load 8 consecutive fp32 and round to a bf16x8 MFMA fragment
__device__ __forceinline__ bf16x8 load8f(const float* __restrict__ p) {
    floatx4 a = *(const floatx4*)p;
    floatx4 b = *(const floatx4*)(p + 4);
    union { bf16x8 v; unsigned int u[4]; } r;
    r.u[0] = pack_bf16(a[0], a[1]);
    r.u[1] = pack_bf16(a[2], a[3]);
    r.u[2] = pack_bf16(b[0], b[1]);
    r.u[3] = pack_bf16(b[2], b[3]);
    return r.v;
}

// ---------------------------------------------------------------------------
// Kernel 1: projection -> PT2 (fragment-tiled bf16) + s_src/s_tgt.
// EXACT round-8 kernel (verified fast).
// PT2 layout:
//   elem(h, f, j) -> (h*64 + (j>>5))*2048 + (f>>4)*512 + ((j>>3)&3)*128
//                    + (f&15)*8 + (j&7)        [per-batch slab]
// ---------------------------------------------------------------------------
__global__ __launch_bounds__(256) void proj_kernel(
    const float* __restrict__ x,      // (BN, NN, FIN) fp32
    const float* __restrict__ wproj,  // (D, FIN) fp32
    const float* __restrict__ ssrc,   // (H, FO) fp32
    const float* __restrict__ stgt,   // (H, FO) fp32
    short* __restrict__ pt,           // (nb) PT2 slabs, 1 MiB each
    float* __restrict__ sS,           // (nb*H, NN) fp32
    float* __restrict__ sT,           // (nb*H, NN) fp32
    int b0)
{
    __shared__ short ptl[64][264];    // [f][j_local], +8 pad (33792 B)

    const int tid  = threadIdx.x;
    const int wave = tid >> 6;
    const int lane = tid & 63;
    const int l16  = lane & 15;
    const int quad = lane >> 4;

    const int b_rel = blockIdx.z;
    const int b  = b0 + b_rel;
    const int h  = blockIdx.y;            // head
    const int j0 = blockIdx.x * 256 + wave * 64;

    floatx4 acc[4][4];
#pragma unroll
    for (int mi = 0; mi < 4; ++mi)
#pragma unroll
        for (int nj = 0; nj < 4; ++nj)
            acc[mi][nj] = (floatx4){0.f, 0.f, 0.f, 0.f};

#pragma unroll
    for (int kc = 0; kc < 4; ++kc) {
        const int c = kc * 32 + quad * 8;
        bf16x8 afr[4], bfr[4];
#pragma unroll
        for (int mi = 0; mi < 4; ++mi) {
            int f = mi * 16 + l16;                // f within head
            int srow = f * H_ + h;                // W_proj row (flat d = f*H+h)
            afr[mi] = load8f(wproj + srow * FIN_ + c);
        }
#pragma unroll
        for (int nj = 0; nj < 4; ++nj) {
            int j = j0 + nj * 16 + l16;
            bfr[nj] = load8f(x + ((size_t)b * NN_ + j) * FIN_ + c);
        }
#pragma unroll
        for (int mi = 0; mi < 4; ++mi)
#pragma unroll
            for (int nj = 0; nj < 4; ++nj)
                acc[mi][nj] = __builtin_amdgcn_mfma_f32_16x16x32_bf16(
                    afr[mi], bfr[nj], acc[mi][nj], 0, 0, 0);
    }

    // ---- stage C-fragments into the [f][j_local] LDS tile ----
    // lane holds (f = mi*16 + quad*4 + r, j_local = wave*64 + nj*16 + l16)
#pragma unroll
    for (int mi = 0; mi < 4; ++mi)
#pragma unroll
        for (int r = 0; r < 4; ++r)
#pragma unroll
            for (int nj = 0; nj < 4; ++nj)
                ptl[mi * 16 + quad * 4 + r][wave * 64 + nj * 16 + l16] =
                    f2bf(acc[mi][nj][r]);

    // ---- score dot-products from fp32 accumulators (register-local) ----
    float wsv[4][4], wtv[4][4];
#pragma unroll
    for (int mi = 0; mi < 4; ++mi)
#pragma unroll
        for (int r = 0; r < 4; ++r) {
            int f = mi * 16 + quad * 4 + r;
            wsv[mi][r] = ssrc[h * FO_ + f];
            wtv[mi][r] = stgt[h * FO_ + f];
        }
    const size_t sbase = ((size_t)b_rel * H_ + h) * NN_;
#pragma unroll
    for (int nj = 0; nj < 4; ++nj) {
        float ps = 0.f, pg = 0.f;
#pragma unroll
        for (int mi = 0; mi < 4; ++mi)
#pragma unroll
            for (int r = 0; r < 4; ++r) {
                ps = fmaf(wsv[mi][r], acc[mi][nj][r], ps);
                pg = fmaf(wtv[mi][r], acc[mi][nj][r], pg);
            }
        ps += __shfl_xor(ps, 16, 64); ps += __shfl_xor(ps, 32, 64);
        pg += __shfl_xor(pg, 16, 64); pg += __shfl_xor(pg, 32, 64);
        if (quad == 0) {
            int j = j0 + nj * 16 + l16;
            sS[sbase + j] = ps;
            sT[sbase + j] = pg;
        }
    }

    __syncthreads();

    // ---- dense PT2 store: block's 32 KB range is CONTIGUOUS in PT2 ----
    const size_t base = ((size_t)b_rel * H_ + h) * (size_t)(64 * 2048)
                      + (size_t)(blockIdx.x * 8) * 2048;
#pragma unroll
    for (int p = 0; p < 8; ++p) {
        const int uid  = p * 256 + tid;           // 0..2047
        const int mi   = (uid >> 6) & 3;          // == wave
        const int l    = uid & 63;                // == lane
        const int tile = uid >> 8;                // wave-uniform
        const int f    = mi * 16 + (l & 15);
        const int js   = tile * 32 + (l >> 4) * 8;
        bf16x8 v = *(const bf16x8*)&ptl[f][js];   // 16B-aligned (264|8, js|8)
        *(bf16x8*)&pt[base + (size_t)uid * 8] = v;  // dense: lane*16B
    }
}

// ---------------------------------------------------------------------------
// Kernel 2: fused attention, 4 heads per block, i-tile = 32 (r12 geometry,
// 157.8 us best). Round-14 change: LDS-resident exp factorization.
//   wv = max(es*et, es2*et2) * ea       (exp monotone => == exp(leaky)+adj)
// et/et2 = exp2(s_tgt*log2e), exp2(.2*s_tgt*log2e) computed in the PREAMBLE
// and kept in LDS (replacing the raw st array) -> zero global-vmem delta
// (the axis r10 lost on); exp2 per wave-jt: 64 -> 16 (ea only, shared by 4
// heads). r13's IT=64 attempt spilled (WRITE_SIZE 221 MB) -> reverted.
// LDS 100 KB (adjs 36864 + et 32768 + et2 32768, union red). Numerics:
// r10's identical factorization passed at the same absmax.
// ---------------------------------------------------------------------------
#define RSTRIDE 65   // LDS row stride (pad +1 col to break bank alignment)
#define WSLOT   (RSTRIDE * 16 + 16)   // 1056 floats per wave slot

__global__ __launch_bounds__(512, 2) void attn_kernel(
    const float* __restrict__ adj,    // (BN, NN, NN) fp32
    const short* __restrict__ pt,     // PT2 slabs (see proj_kernel)
    const float* __restrict__ sS,     // (nb*H, NN) fp32
    const float* __restrict__ sT,     // (nb*H, NN) fp32
    const float* __restrict__ bias,   // (D,) fp32
    float* __restrict__ out,          // (BN, NN, D) fp32
    int b0)
{
    __shared__ union {
        struct {
            float adjs[8][32][36];    // per-wave adj tile (36864 B)
            float et [8][4][256];     // per-wave exp(s_tgt) slices (32768 B)
            float et2[8][4][256];     // per-wave exp(.2 s_tgt) (32768 B)
        } m;
        float red[8][WSLOT];          // cross-wave reduction (33792 B)
    } sm;

    const int tid  = threadIdx.x;
    const int w    = tid >> 6;        // wave = 256-wide j-slice
    const int lane = tid & 63;
    const int l16  = lane & 15;
    const int quad = lane >> 4;
    const int r8   = lane >> 3;       // 0..7  (adj stage row-in-group)
    const int c4   = (lane & 7) * 4;  // 0,4..28 (adj stage col, floats)

    // ---- T1 XCD-aware remap (identity unless full 4-batch grid) ----
    int bx = blockIdx.x, bz = blockIdx.z;
    if (gridDim.z == 4 && gridDim.x == 64) {
        const int flat = bx + 64 * bz;        // HW flat workgroup id (0..255)
        const int xcd  = flat & 7;            // round-robin XCD model
        bz = xcd >> 1;                        // batch: 2 XCDs per batch
        bx = (xcd & 1) * 32 + (flat >> 3);    // i-block within batch
    }
    const int b_rel = bz;
    const int b  = b0 + b_rel;
    const int i0 = bx * 32;

    const short* pt2_b = pt + (size_t)b_rel * H_ * (size_t)(64 * 2048);
    const size_t sb = (size_t)b_rel * H_ * NN_;

    // preamble: stage exp-factorized s_tgt slices for all 4 heads
    // (wave-private; no barrier needed)
    {
        const int t = lane * 4;
#pragma unroll
        for (int h = 0; h < 4; ++h) {
            floatx4 sv = *(const floatx4*)&sT[sb + (size_t)h * NN_ + w * 256 + t];
            floatx4 e1, e2;
#pragma unroll
            for (int k = 0; k < 4; ++k) {
                e1[k] = EXP2(sv[k] * LOG2E);
                e2[k] = EXP2(sv[k] * C2F);
            }
            *(floatx4*)&sm.m.et [w][h][t] = e1;
            *(floatx4*)&sm.m.et2[w][h][t] = e2;
        }
    }

    // per-lane exp-factorized s_src for my two i-rows, all heads
    float es[2][4], es2[2][4];
#pragma unroll
    for (int sub = 0; sub < 2; ++sub)
#pragma unroll
        for (int h = 0; h < 4; ++h) {
            float sv = sS[sb + (size_t)h * NN_ + i0 + sub * 16 + l16];
            es [sub][h] = EXP2(sv * LOG2E);
            es2[sub][h] = EXP2(sv * C2F);
        }

    // adj stage base: rows i0.., cols w*256..
    const float* adj_base = adj + ((size_t)b * NN_ + i0) * NN_ + w * 256;

    floatx4 acc[2][4][4];             // [i-sub][head][f-block], 128 regs
#pragma unroll
    for (int sub = 0; sub < 2; ++sub)
#pragma unroll
        for (int h = 0; h < 4; ++h)
#pragma unroll
            for (int K = 0; K < 4; ++K)
                acc[sub][h][K] = (floatx4){0.f, 0.f, 0.f, 0.f};
    float ls[2][4] = {{0.f, 0.f, 0.f, 0.f}, {0.f, 0.f, 0.f, 0.f}};

    // prologue: dense-load + stage adj tile jt=0 (32 rows)
    floatx4 ar0 = *(const floatx4*)(adj_base + (size_t)r8 * NN_ + c4);
    floatx4 ar1 = *(const floatx4*)(adj_base + (size_t)(8 + r8) * NN_ + c4);
    floatx4 ar2 = *(const floatx4*)(adj_base + (size_t)(16 + r8) * NN_ + c4);
    floatx4 ar3 = *(const floatx4*)(adj_base + (size_t)(24 + r8) * NN_ + c4);
    *(floatx4*)&sm.m.adjs[w][r8][c4]      = ar0;
    *(floatx4*)&sm.m.adjs[w][8 + r8][c4]  = ar1;
    *(floatx4*)&sm.m.adjs[w][16 + r8][c4] = ar2;
    *(floatx4*)&sm.m.adjs[w][24 + r8][c4] = ar3;

    const int lo8 = lane * 8;         // PT2 per-lane element offset

#pragma unroll
    for (int jt = 0; jt < 8; ++jt) {              // 8 iters x 32 j per wave
        const int o  = jt * 32;                   // static element offset
        const int qo = quad * 8;

        // T14 issue-early: dense global loads for the NEXT adj tile
        if (jt < 7) {
            ar0 = *(const floatx4*)(adj_base + (size_t)r8 * NN_ + o + 32 + c4);
            ar1 = *(const floatx4*)(adj_base + (size_t)(8 + r8) * NN_ + o + 32 + c4);
            ar2 = *(const floatx4*)(adj_base + (size_t)(16 + r8) * NN_ + o + 32 + c4);
            ar3 = *(const floatx4*)(adj_base + (size_t)(24 + r8) * NN_ + o + 32 + c4);
        }

        // A-values + ea = exp2(adj*log2e) for both i-subtiles
        // (16 exp2/jt, shared across all 4 heads -- was 64)
        floatx4 eaA[2], eaB[2];
#pragma unroll
        for (int sub = 0; sub < 2; ++sub) {
            floatx4 ajA = *(const floatx4*)&sm.m.adjs[w][sub * 16 + l16][qo];
            floatx4 ajB = *(const floatx4*)&sm.m.adjs[w][sub * 16 + l16][qo + 4];
#pragma unroll
            for (int k = 0; k < 4; ++k) {
                eaA[sub][k] = EXP2(ajA[k] * LOG2E);
                eaB[sub][k] = EXP2(ajB[k] * LOG2E);
            }
        }

#pragma unroll
        for (int u = 0; u < 4; ++u) {
            // dense 1 KB fragment loads from PT2 (uniform base + lane*16B),
            // shared by BOTH i-subtiles
            const short* fb = pt2_b + ((size_t)u * 64 + (w * 8 + jt)) * 2048 + lo8;
            bf16x8 bfr[4];
#pragma unroll
            for (int K = 0; K < 4; ++K)
                bfr[K] = *(const bf16x8*)(fb + K * 512);

            // et/et2 broadcast reads from LDS (quad-uniform 16B)
            const float* etp  = &sm.m.et [w][u][qo];
            const float* et2p = &sm.m.et2[w][u][qo];
            floatx4 etA  = *(const floatx4*)(etp + o);
            floatx4 etB  = *(const floatx4*)(etp + o + 4);
            floatx4 et2A = *(const floatx4*)(et2p + o);
            floatx4 et2B = *(const floatx4*)(et2p + o + 4);

#pragma unroll
            for (int sub = 0; sub < 2; ++sub) {
                const float eu = es[sub][u], eu2 = es2[sub][u];
                float w0 = fmaxf(eu * etA[0], eu2 * et2A[0]) * eaA[sub][0];
                float w1 = fmaxf(eu * etA[1], eu2 * et2A[1]) * eaA[sub][1];
                float w2 = fmaxf(eu * etA[2], eu2 * et2A[2]) * eaA[sub][2];
                float w3 = fmaxf(eu * etA[3], eu2 * et2A[3]) * eaA[sub][3];
                float w4 = fmaxf(eu * etB[0], eu2 * et2B[0]) * eaB[sub][0];
                float w5 = fmaxf(eu * etB[1], eu2 * et2B[1]) * eaB[sub][1];
                float w6 = fmaxf(eu * etB[2], eu2 * et2B[2]) * eaB[sub][2];
                float w7 = fmaxf(eu * etB[3], eu2 * et2B[3]) * eaB[sub][3];
                ls[sub][u] += ((w0 + w1) + (w2 + w3)) + ((w4 + w5) + (w6 + w7));
                union { bf16x8 v; unsigned int u4[4]; } a0;
                a0.u4[0] = pack_bf16(w0, w1);
                a0.u4[1] = pack_bf16(w2, w3);
                a0.u4[2] = pack_bf16(w4, w5);
                a0.u4[3] = pack_bf16(w6, w7);
#pragma unroll
                for (int K = 0; K < 4; ++K)
                    acc[sub][u][K] = __builtin_amdgcn_mfma_f32_16x16x32_bf16(
                        a0.v, bfr[K], acc[sub][u][K], 0, 0, 0);
            }
        }

        // T14 write-late: stage next tile after this tile's LDS reads
        if (jt < 7) {
            *(floatx4*)&sm.m.adjs[w][r8][c4]      = ar0;
            *(floatx4*)&sm.m.adjs[w][8 + r8][c4]  = ar1;
            *(floatx4*)&sm.m.adjs[w][16 + r8][c4] = ar2;
            *(floatx4*)&sm.m.adjs[w][24 + r8][c4] = ar3;
        }
    }

    // wave-local row-sums over quads (row = sub*16 + l16 in A-layout)
#pragma unroll
    for (int sub = 0; sub < 2; ++sub)
#pragma unroll
        for (int h = 0; h < 4; ++h) {
            ls[sub][h] += __shfl_xor(ls[sub][h], 16, 64);
            ls[sub][h] += __shfl_xor(ls[sub][h], 32, 64);
        }

    // epilogue: 8 chunks (sub x head) of 16 rows; 8-wave LDS reduction each
#pragma unroll
    for (int sub = 0; sub < 2; ++sub)
#pragma unroll
    for (int h = 0; h < 4; ++h) {
        __syncthreads();   // first: all main-loop LDS reads done; then: prev chunk
#pragma unroll
        for (int K = 0; K < 4; ++K)
#pragma unroll
            for (int r = 0; r < 4; ++r)
                sm.red[w][(quad * 4 + r) * RSTRIDE + K * 16 + l16] = acc[sub][h][K][r];
        if (quad == 0)
            sm.red[w][16 * RSTRIDE + l16] = ls[sub][h];
        __syncthreads();
#pragma unroll
        for (int p = 0; p < 2; ++p) {
            int e   = tid + p * 512;
            int row = e >> 6;
            int col = e & 63;
            float s = 0.f, l = 0.f;
#pragma unroll
            for (int ww = 0; ww < 8; ++ww) {
                s += sm.red[ww][row * RSTRIDE + col];
                l += sm.red[ww][16 * RSTRIDE + row];
            }
            float v = s / l + bias[h * FO_ + col];
            v = (v > 0.f) ? v : expm1f(v);        // elu (fp32 out)
            out[((size_t)b * NN_ + i0 + sub * 16 + row) * D_ + h * FO_ + col] = v;
        }
    }
}

// ---------------------------------------------------------------------------
extern "C" void kernel_launch(void* const* d_in, const int* in_sizes, int n_in,
                              void* d_out, int out_size, void* d_ws, size_t ws_size,
                              hipStream_t stream) {
    const float* x     = (const float*)d_in[0];   // (4,2048,128) fp32
    const float* adj   = (const float*)d_in[1];   // (4,2048,2048) fp32
    const float* wproj = (const float*)d_in[2];   // (256,128) fp32
    const float* ssrc  = (const float*)d_in[3];   // (4,64) fp32
    const float* stgt  = (const float*)d_in[4];   // (4,64) fp32
    const float* bias  = (const float*)d_in[5];   // (256,) fp32
    float* out = (float*)d_out;                   // (4,2048,256) fp32

    // ws layout per batch: PT2 slab (1 MiB) + s_src/s_tgt (64 KiB)
    const size_t SLAB  = (size_t)D_ * NN_ * 2;          // bf16 PT2
    const size_t SSLAB = (size_t)2 * H_ * NN_ * 4;      // fp32 sS+sT
    int nb = (int)(ws_size / (SLAB + SSLAB));
    if (nb < 1) nb = 1;
    if (nb > 4) nb = 4;

    short* pt = (short*)d_ws;
    float* sv = (float*)((char*)d_ws + (size_t)nb * SLAB);
    float* sS = sv;
    float* sT = sv + (size_t)nb * H_ * NN_;

    for (int bb0 = 0; bb0 < BN_; bb0 += nb) {
        int cnt = (BN_ - bb0 < nb) ? (BN_ - bb0) : nb;
        proj_kernel<<<dim3(NN_ / 256, H_, cnt), 256, 0, stream>>>(
            x, wproj, ssrc, stgt, pt, sS, sT, bb0);
        attn_kernel<<<dim3(NN_ / 32, 1, cnt), 512, 0, stream>>>(
            adj, pt, sS, sT, bias, out, bb0);
    }
}

// Round 16
// 158.914 us; speedup vs baseline: 2.0364x; 2.0364x over previous
//
#include <hip/hip_runtime.h>
#include <hip/hip_bf16.h>
#include <math.h>

// Problem constants (BN, N, FIN, FO, H) from the reference
#define BN_   4
#define NN_   2048
#define FIN_  128
#define FO_   64
#define H_    4
#define D_    256   // FO*H

typedef __attribute__((ext_vector_type(8))) short bf16x8;   // 8 bf16 = 4 VGPRs
typedef __attribute__((ext_vector_type(4))) float floatx4;  // MFMA C/D frag

#define LOG2E 1.4426950408889634f

#if __has_builtin(__builtin_amdgcn_exp2f)
#define EXP2(x) __builtin_amdgcn_exp2f(x)
#else
#define EXP2(x) exp2f(x)
#endif

__device__ __forceinline__ float bf2f(short u) {
    union { unsigned int i; float f; } v;
    v.i = ((unsigned int)(unsigned short)u) << 16;
    return v.f;
}
__device__ __forceinline__ short f2bf(float f) {
    union { float f; unsigned int u; } v; v.f = f;
    unsigned int r = v.u + 0x7fffu + ((v.u >> 16) & 1u);  // RNE
    return (short)(unsigned short)(r >> 16);
}

// pack two floats to two bf16 (RNE) in one dword; elem0 in low 16 bits
#if defined(__BF16_MANT_DIG__)
typedef __bf16 bfr2 __attribute__((ext_vector_type(2)));
__device__ __forceinline__ unsigned int pack_bf16(float a, float b) {
    union { bfr2 h; unsigned int u; } v;
    v.h = (bfr2){(__bf16)a, (__bf16)b};
    return v.u;
}
#else
__device__ __forceinline__ unsigned int pack_bf16(float a, float b) {
    return ((unsigned int)(unsigned short)f2bf(a)) |
           (((unsigned int)(unsigned short)f2bf(b)) << 16);
}
#endif

// load 8 consecutive fp32 and round to a bf16x8 MFMA fragment
__device__ __forceinline__ bf16x8 load8f(const float* __restrict__ p) {
    floatx4 a = *(const floatx4*)p;
    floatx4 b = *(const floatx4*)(p + 4);
    union { bf16x8 v; unsigned int u[4]; } r;
    r.u[0] = pack_bf16(a[0], a[1]);
    r.u[1] = pack_bf16(a[2], a[3]);
    r.u[2] = pack_bf16(b[0], b[1]);
    r.u[3] = pack_bf16(b[2], b[3]);
    return r.v;
}

// attention score -> exp weight (bit-identical across rounds)
__device__ __forceinline__ float score_exp(float ssv, float stv, float av) {
    float s = ssv + stv;
    s = fmaxf(s, 0.2f * s);            // leaky_relu(0.2)
    return EXP2((s + av) * LOG2E);
}

// ---------------------------------------------------------------------------
// Kernel 1: projection -> PT2 (fragment-tiled bf16) + s_src/s_tgt.
// EXACT round-8 kernel (verified fast).
// PT2 layout:
//   elem(h, f, j) -> (h*64 + (j>>5))*2048 + (f>>4)*512 + ((j>>3)&3)*128
//                    + (f&15)*8 + (j&7)        [per-batch slab]
// ---------------------------------------------------------------------------
__global__ __launch_bounds__(256) void proj_kernel(
    const float* __restrict__ x,      // (BN, NN, FIN) fp32
    const float* __restrict__ wproj,  // (D, FIN) fp32
    const float* __restrict__ ssrc,   // (H, FO) fp32
    const float* __restrict__ stgt,   // (H, FO) fp32
    short* __restrict__ pt,           // (nb) PT2 slabs, 1 MiB each
    float* __restrict__ sS,           // (nb*H, NN) fp32
    float* __restrict__ sT,           // (nb*H, NN) fp32
    int b0)
{
    __shared__ short ptl[64][264];    // [f][j_local], +8 pad (33792 B)

    const int tid  = threadIdx.x;
    const int wave = tid >> 6;
    const int lane = tid & 63;
    const int l16  = lane & 15;
    const int quad = lane >> 4;

    const int b_rel = blockIdx.z;
    const int b  = b0 + b_rel;
    const int h  = blockIdx.y;            // head
    const int j0 = blockIdx.x * 256 + wave * 64;

    floatx4 acc[4][4];
#pragma unroll
    for (int mi = 0; mi < 4; ++mi)
#pragma unroll
        for (int nj = 0; nj < 4; ++nj)
            acc[mi][nj] = (floatx4){0.f, 0.f, 0.f, 0.f};

#pragma unroll
    for (int kc = 0; kc < 4; ++kc) {
        const int c = kc * 32 + quad * 8;
        bf16x8 afr[4], bfr[4];
#pragma unroll
        for (int mi = 0; mi < 4; ++mi) {
            int f = mi * 16 + l16;                // f within head
            int srow = f * H_ + h;                // W_proj row (flat d = f*H+h)
            afr[mi] = load8f(wproj + srow * FIN_ + c);
        }
#pragma unroll
        for (int nj = 0; nj < 4; ++nj) {
            int j = j0 + nj * 16 + l16;
            bfr[nj] = load8f(x + ((size_t)b * NN_ + j) * FIN_ + c);
        }
#pragma unroll
        for (int mi = 0; mi < 4; ++mi)
#pragma unroll
            for (int nj = 0; nj < 4; ++nj)
                acc[mi][nj] = __builtin_amdgcn_mfma_f32_16x16x32_bf16(
                    afr[mi], bfr[nj], acc[mi][nj], 0, 0, 0);
    }

    // ---- stage C-fragments into the [f][j_local] LDS tile ----
    // lane holds (f = mi*16 + quad*4 + r, j_local = wave*64 + nj*16 + l16)
#pragma unroll
    for (int mi = 0; mi < 4; ++mi)
#pragma unroll
        for (int r = 0; r < 4; ++r)
#pragma unroll
            for (int nj = 0; nj < 4; ++nj)
                ptl[mi * 16 + quad * 4 + r][wave * 64 + nj * 16 + l16] =
                    f2bf(acc[mi][nj][r]);

    // ---- score dot-products from fp32 accumulators (register-local) ----
    float wsv[4][4], wtv[4][4];
#pragma unroll
    for (int mi = 0; mi < 4; ++mi)
#pragma unroll
        for (int r = 0; r < 4; ++r) {
            int f = mi * 16 + quad * 4 + r;
            wsv[mi][r] = ssrc[h * FO_ + f];
            wtv[mi][r] = stgt[h * FO_ + f];
        }
    const size_t sbase = ((size_t)b_rel * H_ + h) * NN_;
#pragma unroll
    for (int nj = 0; nj < 4; ++nj) {
        float ps = 0.f, pg = 0.f;
#pragma unroll
        for (int mi = 0; mi < 4; ++mi)
#pragma unroll
            for (int r = 0; r < 4; ++r) {
                ps = fmaf(wsv[mi][r], acc[mi][nj][r], ps);
                pg = fmaf(wtv[mi][r], acc[mi][nj][r], pg);
            }
        ps += __shfl_xor(ps, 16, 64); ps += __shfl_xor(ps, 32, 64);
        pg += __shfl_xor(pg, 16, 64); pg += __shfl_xor(pg, 32, 64);
        if (quad == 0) {
            int j = j0 + nj * 16 + l16;
            sS[sbase + j] = ps;
            sT[sbase + j] = pg;
        }
    }

    __syncthreads();

    // ---- dense PT2 store: block's 32 KB range is CONTIGUOUS in PT2 ----
    const size_t base = ((size_t)b_rel * H_ + h) * (size_t)(64 * 2048)
                      + (size_t)(blockIdx.x * 8) * 2048;
#pragma unroll
    for (int p = 0; p < 8; ++p) {
        const int uid  = p * 256 + tid;           // 0..2047
        const int mi   = (uid >> 6) & 3;          // == wave
        const int l    = uid & 63;                // == lane
        const int tile = uid >> 8;                // wave-uniform
        const int f    = mi * 16 + (l & 15);
        const int js   = tile * 32 + (l >> 4) * 8;
        bf16x8 v = *(const bf16x8*)&ptl[f][js];   // 16B-aligned (264|8, js|8)
        *(bf16x8*)&pt[base + (size_t)uid * 8] = v;  // dense: lane*16B
    }
}

// ---------------------------------------------------------------------------
// Kernel 2: fused attention, 4 heads per block, i-tile = 32.
//
// FINAL (= round-12 verified best: 157.8 us total, attn 45.3 us, no spill).
// Session-established law: attn time tracks main-loop vmem instrs/CU
// (~56 cyc per dense 1 KB wave-load); locality (r11), occupancy (r1/r5),
// prefetch depth (r4), and exp2 count (r10/r14) are non-levers. This
// geometry (IT=32, 4 heads, 20 loads/jt, acc=128 AGPRs) sits exactly at
// the 256-VGPR unified cap; r13 (IT=64) and r14 (exp factorization) both
// spilled (WRITE_SIZE 221/419 MB) and regressed 3-5x. Do not add live
// state to this main loop.
// ---------------------------------------------------------------------------
#define RSTRIDE 65   // LDS row stride (pad +1 col to break bank alignment)
#define WSLOT   (RSTRIDE * 16 + 16)   // 1056 floats per wave slot

__global__ __launch_bounds__(512, 2) void attn_kernel(
    const float* __restrict__ adj,    // (BN, NN, NN) fp32
    const short* __restrict__ pt,     // PT2 slabs (see proj_kernel)
    const float* __restrict__ sS,     // (nb*H, NN) fp32
    const float* __restrict__ sT,     // (nb*H, NN) fp32
    const float* __restrict__ bias,   // (D,) fp32
    float* __restrict__ out,          // (BN, NN, D) fp32
    int b0)
{
    __shared__ union {
        struct {
            float adjs[8][32][36];    // per-wave adj tile (36864 B)
            float st[8][4][256];      // per-wave s_tgt slices (32768 B)
        } m;
        float red[8][WSLOT];          // cross-wave reduction (33792 B)
    } sm;

    const int tid  = threadIdx.x;
    const int w    = tid >> 6;        // wave = 256-wide j-slice
    const int lane = tid & 63;
    const int l16  = lane & 15;
    const int quad = lane >> 4;
    const int r8   = lane >> 3;       // 0..7  (adj stage row-in-group)
    const int c4   = (lane & 7) * 4;  // 0,4..28 (adj stage col, floats)

    // ---- T1 XCD-aware remap (identity unless full 4-batch grid) ----
    int bx = blockIdx.x, bz = blockIdx.z;
    if (gridDim.z == 4 && gridDim.x == 64) {
        const int flat = bx + 64 * bz;        // HW flat workgroup id (0..255)
        const int xcd  = flat & 7;            // round-robin XCD model
        bz = xcd >> 1;                        // batch: 2 XCDs per batch
        bx = (xcd & 1) * 32 + (flat >> 3);    // i-block within batch
    }
    const int b_rel = bz;
    const int b  = b0 + b_rel;
    const int i0 = bx * 32;

    const short* pt2_b = pt + (size_t)b_rel * H_ * (size_t)(64 * 2048);
    const size_t sb = (size_t)b_rel * H_ * NN_;

    // stage s_tgt slices for all 4 heads (wave-private; no barrier needed)
    {
        const int t = lane * 4;
#pragma unroll
        for (int h = 0; h < 4; ++h)
            *(floatx4*)&sm.m.st[w][h][t] =
                *(const floatx4*)&sT[sb + (size_t)h * NN_ + w * 256 + t];
    }

    // per-lane s_src for my two i-rows (sub*16 + l16), all heads
    float ssv[2][4];
#pragma unroll
    for (int sub = 0; sub < 2; ++sub)
#pragma unroll
        for (int h = 0; h < 4; ++h)
            ssv[sub][h] = sS[sb + (size_t)h * NN_ + i0 + sub * 16 + l16];

    // adj stage base: rows i0.., cols w*256..
    const float* adj_base = adj + ((size_t)b * NN_ + i0) * NN_ + w * 256;

    floatx4 acc[2][4][4];             // [i-sub][head][f-block], 128 regs
#pragma unroll
    for (int sub = 0; sub < 2; ++sub)
#pragma unroll
        for (int h = 0; h < 4; ++h)
#pragma unroll
            for (int K = 0; K < 4; ++K)
                acc[sub][h][K] = (floatx4){0.f, 0.f, 0.f, 0.f};
    float ls[2][4] = {{0.f, 0.f, 0.f, 0.f}, {0.f, 0.f, 0.f, 0.f}};

    // prologue: dense-load + stage adj tile jt=0 (32 rows)
    floatx4 ar0 = *(const floatx4*)(adj_base + (size_t)r8 * NN_ + c4);
    floatx4 ar1 = *(const floatx4*)(adj_base + (size_t)(8 + r8) * NN_ + c4);
    floatx4 ar2 = *(const floatx4*)(adj_base + (size_t)(16 + r8) * NN_ + c4);
    floatx4 ar3 = *(const floatx4*)(adj_base + (size_t)(24 + r8) * NN_ + c4);
    *(floatx4*)&sm.m.adjs[w][r8][c4]      = ar0;
    *(floatx4*)&sm.m.adjs[w][8 + r8][c4]  = ar1;
    *(floatx4*)&sm.m.adjs[w][16 + r8][c4] = ar2;
    *(floatx4*)&sm.m.adjs[w][24 + r8][c4] = ar3;

    const int lo8 = lane * 8;         // PT2 per-lane element offset

#pragma unroll
    for (int jt = 0; jt < 8; ++jt) {              // 8 iters x 32 j per wave
        const int o  = jt * 32;                   // static element offset
        const int qo = quad * 8;

        // T14 issue-early: dense global loads for the NEXT adj tile
        if (jt < 7) {
            ar0 = *(const floatx4*)(adj_base + (size_t)r8 * NN_ + o + 32 + c4);
            ar1 = *(const floatx4*)(adj_base + (size_t)(8 + r8) * NN_ + o + 32 + c4);
            ar2 = *(const floatx4*)(adj_base + (size_t)(16 + r8) * NN_ + o + 32 + c4);
            ar3 = *(const floatx4*)(adj_base + (size_t)(24 + r8) * NN_ + o + 32 + c4);
        }

        // A-values for both i-subtiles from LDS (wave-private, staged)
        floatx4 ajA[2], ajB[2];
#pragma unroll
        for (int sub = 0; sub < 2; ++sub) {
            ajA[sub] = *(const floatx4*)&sm.m.adjs[w][sub * 16 + l16][qo];
            ajB[sub] = *(const floatx4*)&sm.m.adjs[w][sub * 16 + l16][qo + 4];
        }

#pragma unroll
        for (int u = 0; u < 4; ++u) {
            // dense 1 KB fragment loads from PT2 (uniform base + lane*16B),
            // shared by BOTH i-subtiles (the round-12 reuse lever)
            const short* fb = pt2_b + ((size_t)u * 64 + (w * 8 + jt)) * 2048 + lo8;
            bf16x8 bfr[4];
#pragma unroll
            for (int K = 0; K < 4; ++K)
                bfr[K] = *(const bf16x8*)(fb + K * 512);

            const float* stp = &sm.m.st[w][u][qo];
            floatx4 stA = *(const floatx4*)(stp + o);
            floatx4 stB = *(const floatx4*)(stp + o + 4);

#pragma unroll
            for (int sub = 0; sub < 2; ++sub) {
                const float sv = ssv[sub][u];
                float w0 = score_exp(sv, stA[0], ajA[sub][0]);
                float w1 = score_exp(sv, stA[1], ajA[sub][1]);
                float w2 = score_exp(sv, stA[2], ajA[sub][2]);
                float w3 = score_exp(sv, stA[3], ajA[sub][3]);
                float w4 = score_exp(sv, stB[0], ajB[sub][0]);
                float w5 = score_exp(sv, stB[1], ajB[sub][1]);
                float w6 = score_exp(sv, stB[2], ajB[sub][2]);
                float w7 = score_exp(sv, stB[3], ajB[sub][3]);
                ls[sub][u] += ((w0 + w1) + (w2 + w3)) + ((w4 + w5) + (w6 + w7));
                union { bf16x8 v; unsigned int u4[4]; } a0;
                a0.u4[0] = pack_bf16(w0, w1);
                a0.u4[1] = pack_bf16(w2, w3);
                a0.u4[2] = pack_bf16(w4, w5);
                a0.u4[3] = pack_bf16(w6, w7);
#pragma unroll
                for (int K = 0; K < 4; ++K)
                    acc[sub][u][K] = __builtin_amdgcn_mfma_f32_16x16x32_bf16(
                        a0.v, bfr[K], acc[sub][u][K], 0, 0, 0);
            }
        }

        // T14 write-late: stage next tile after this tile's LDS reads
        if (jt < 7) {
            *(floatx4*)&sm.m.adjs[w][r8][c4]      = ar0;
            *(floatx4*)&sm.m.adjs[w][8 + r8][c4]  = ar1;
            *(floatx4*)&sm.m.adjs[w][16 + r8][c4] = ar2;
            *(floatx4*)&sm.m.adjs[w][24 + r8][c4] = ar3;
        }
    }

    // wave-local row-sums over quads (row = sub*16 + l16 in A-layout)
#pragma unroll
    for (int sub = 0; sub < 2; ++sub)
#pragma unroll
        for (int h = 0; h < 4; ++h) {
            ls[sub][h] += __shfl_xor(ls[sub][h], 16, 64);
            ls[sub][h] += __shfl_xor(ls[sub][h], 32, 64);
        }

    // epilogue: 8 chunks (sub x head) of 16 rows; 8-wave LDS reduction each
#pragma unroll
    for (int sub = 0; sub < 2; ++sub)
#pragma unroll
    for (int h = 0; h < 4; ++h) {
        __syncthreads();   // first: all main-loop LDS reads done; then: prev chunk
#pragma unroll
        for (int K = 0; K < 4; ++K)
#pragma unroll
            for (int r = 0; r < 4; ++r)
                sm.red[w][(quad * 4 + r) * RSTRIDE + K * 16 + l16] = acc[sub][h][K][r];
        if (quad == 0)
            sm.red[w][16 * RSTRIDE + l16] = ls[sub][h];
        __syncthreads();
#pragma unroll
        for (int p = 0; p < 2; ++p) {
            int e   = tid + p * 512;
            int row = e >> 6;
            int col = e & 63;
            float s = 0.f, l = 0.f;
#pragma unroll
            for (int ww = 0; ww < 8; ++ww) {
                s += sm.red[ww][row * RSTRIDE + col];
                l += sm.red[ww][16 * RSTRIDE + row];
            }
            float v = s / l + bias[h * FO_ + col];
            v = (v > 0.f) ? v : expm1f(v);        // elu (fp32 out)
            out[((size_t)b * NN_ + i0 + sub * 16 + row) * D_ + h * FO_ + col] = v;
        }
    }
}

// ---------------------------------------------------------------------------
extern "C" void kernel_launch(void* const* d_in, const int* in_sizes, int n_in,
                              void* d_out, int out_size, void* d_ws, size_t ws_size,
                              hipStream_t stream) {
    const float* x     = (const float*)d_in[0];   // (4,2048,128) fp32
    const float* adj   = (const float*)d_in[1];   // (4,2048,2048) fp32
    const float* wproj = (const float*)d_in[2];   // (256,128) fp32
    const float* ssrc  = (const float*)d_in[3];   // (4,64) fp32
    const float* stgt  = (const float*)d_in[4];   // (4,64) fp32
    const float* bias  = (const float*)d_in[5];   // (256,) fp32
    float* out = (float*)d_out;                   // (4,2048,256) fp32

    // ws layout per batch: PT2 slab (1 MiB) + s_src/s_tgt (64 KiB)
    const size_t SLAB  = (size_t)D_ * NN_ * 2;          // bf16 PT2
    const size_t SSLAB = (size_t)2 * H_ * NN_ * 4;      // fp32 sS+sT
    int nb = (int)(ws_size / (SLAB + SSLAB));
    if (nb < 1) nb = 1;
    if (nb > 4) nb = 4;

    short* pt = (short*)d_ws;
    float* sv = (float*)((char*)d_ws + (size_t)nb * SLAB);
    float* sS = sv;
    float* sT = sv + (size_t)nb * H_ * NN_;

    for (int bb0 = 0; bb0 < BN_; bb0 += nb) {
        int cnt = (BN_ - bb0 < nb) ? (BN_ - bb0) : nb;
        proj_kernel<<<dim3(NN_ / 256, H_, cnt), 256, 0, stream>>>(
            x, wproj, ssrc, stgt, pt, sS, sT, bb0);
        attn_kernel<<<dim3(NN_ / 32, 1, cnt), 512, 0, stream>>>(
            adj, pt, sS, sT, bias, out, bb0);
    }
}